// Round 12
// baseline (515.265 us; speedup 1.0000x reference)
//
#include <hip/hip_runtime.h>
#include <math.h>

typedef __attribute__((ext_vector_type(8))) short bf16x8;
typedef __attribute__((ext_vector_type(4))) float f32x4;

__device__ __forceinline__ unsigned short f2bf_rtne(float v) {
    unsigned u = __float_as_uint(v);
    u += 0x7FFFu + ((u >> 16) & 1u);
    return (unsigned short)(u >> 16);
}

// ---------------- CSR build ----------------
__global__ __launch_bounds__(256) void hist_k(const int* __restrict__ dst, int* __restrict__ deg, int e) {
    int i4 = (blockIdx.x * 256 + threadIdx.x) * 4;
    if (i4 + 3 < e) {
        int4 d = *(const int4*)(dst + i4);
        atomicAdd(&deg[d.x], 1);
        atomicAdd(&deg[d.y], 1);
        atomicAdd(&deg[d.z], 1);
        atomicAdd(&deg[d.w], 1);
    } else {
        for (int j = i4; j < e; j++) atomicAdd(&deg[dst[j]], 1);
    }
}

__global__ __launch_bounds__(256) void scan1_k(const int* __restrict__ deg, int* __restrict__ rowptr,
                                               int* __restrict__ bsum, int n) {
    __shared__ int sh[256];
    int tid = threadIdx.x;
    int sid = blockIdx.x * 256 + tid;
    int v = (sid < n) ? deg[sid] : 0;
    sh[tid] = v; __syncthreads();
    for (int off = 1; off < 256; off <<= 1) {
        int t = (tid >= off) ? sh[tid - off] : 0;
        __syncthreads();
        sh[tid] += t;
        __syncthreads();
    }
    if (sid < n) rowptr[sid + 1] = sh[tid];
    if (tid == 255) bsum[blockIdx.x] = sh[255];
}

__global__ __launch_bounds__(512) void scan2_k(int* __restrict__ bsum, int nb) {
    __shared__ int sh[512];
    int tid = threadIdx.x;
    sh[tid] = (tid < nb) ? bsum[tid] : 0;
    __syncthreads();
    for (int off = 1; off < 512; off <<= 1) {
        int t = (tid >= off) ? sh[tid - off] : 0;
        __syncthreads();
        sh[tid] += t;
        __syncthreads();
    }
    if (tid < nb) bsum[tid] = sh[tid];
}

// finalizes rowptr AND initializes cursor = rowptr (fill uses cursor directly)
__global__ __launch_bounds__(256) void scan3_k(int* __restrict__ rowptr, int* __restrict__ cursor,
                                               const int* __restrict__ bsum, int n) {
    int sid = blockIdx.x * 256 + threadIdx.x;
    if (sid == 0) { rowptr[0] = 0; cursor[0] = 0; }
    if (sid < n) {
        int v = rowptr[sid + 1];
        if (blockIdx.x > 0) v += bsum[blockIdx.x - 1];
        rowptr[sid + 1] = v;
        cursor[sid + 1] = v;
    }
}

__global__ __launch_bounds__(256) void fill_k(const int* __restrict__ src, const int* __restrict__ dst,
                                              int* __restrict__ cursor, int* __restrict__ csrc, int e) {
    int i4 = (blockIdx.x * 256 + threadIdx.x) * 4;
    if (i4 + 3 < e) {
        int4 s = *(const int4*)(src + i4);
        int4 d = *(const int4*)(dst + i4);
        int p0 = atomicAdd(&cursor[d.x], 1);
        int p1 = atomicAdd(&cursor[d.y], 1);
        int p2 = atomicAdd(&cursor[d.z], 1);
        int p3 = atomicAdd(&cursor[d.w], 1);
        csrc[p0] = s.x; csrc[p1] = s.y; csrc[p2] = s.z; csrc[p3] = s.w;
    } else {
        for (int j = i4; j < e; j++) {
            int pos = atomicAdd(&cursor[dst[j]], 1);
            csrc[pos] = src[j];
        }
    }
}

// ---------------- W -> packed hi/lo bf16 MFMA fragments ----------------
// Bp layout: [ks=4][slot=16][lane=64][j=8] shorts, slot = 2n (hi) / 2n+1 (lo).
__global__ __launch_bounds__(256) void wconv_k(const float* __restrict__ W, unsigned short* __restrict__ Bp) {
    int idx = blockIdx.x * 256 + threadIdx.x;    // 0..16383 = (k, ncol)
    int k = idx >> 7, nc = idx & 127;
    float v = W[idx];
    unsigned short h = f2bf_rtne(v);
    float hf = __uint_as_float((unsigned)h << 16);
    unsigned short lo = f2bf_rtne(v - hf);
    int n = nc >> 4, l15 = nc & 15, ks = k >> 5, lhi = (k >> 3) & 3, j = k & 7;
    int lanei = lhi * 16 + l15;
    Bp[(((ks * 16 + 2 * n) * 64) + lanei) * 8 + j] = h;
    Bp[(((ks * 16 + 2 * n + 1) * 64) + lanei) * 8 + j] = lo;
}

// ---------------- split-bf16 MFMA GEMM: C[M,128] = A @ W, fused el/er ----------------
// A*W ~= Ah*Wh + Ah*Wl + Al*Wh. Round-12: TWO 128-row tiles per block (grid 512,
// t1 = b + 512): B staged once for both (halves Bp re-read), A for BOTH tiles
// hoisted into regs before the single barrier -> one latency exposure per 2 tiles,
// tile-0 C-stores overlap tile-1 MFMAs. K-loop reg+LDS only (round-8 lesson).
__global__ __launch_bounds__(256) void gemm_mfma_k(const float* __restrict__ A,
        const unsigned short* __restrict__ Bp,
        const float* __restrict__ alp, const float* __restrict__ arp,
        float* __restrict__ C, float* __restrict__ el, float* __restrict__ er, int M, int T) {
    __shared__ short Bs[4][16][64][8];   // 64 KB -> 2 blocks/CU
    int tid = threadIdx.x;
    int wv = tid >> 6, lane = tid & 63;
    int l15 = lane & 15, lhi = lane >> 4;

    // stage packed B (hi+lo, full K = 64KB): pure linear copy, 16 float4/thread
    {
        const float4* g = (const float4*)Bp;
        float4* s = (float4*)&Bs[0][0][0][0];
        #pragma unroll
        for (int p = 0; p < 16; p++) s[tid + p * 256] = g[tid + p * 256];
    }

    int t0 = blockIdx.x;
    int t1 = blockIdx.x + gridDim.x;
    int mb0 = t0 * 128 + wv * 32;
    int mb1 = t1 * 128 + wv * 32;

    // hoist A for both tiles: 32 independent float4s in flight alongside B staging
    float4 A0a[4][2], A0b[4][2], A1a[4][2], A1b[4][2];
    {
        const float* p0 = A + (size_t)min(mb0 + l15, M - 1) * 128 + lhi * 8;
        const float* p1 = A + (size_t)min(mb0 + 16 + l15, M - 1) * 128 + lhi * 8;
        #pragma unroll
        for (int ks = 0; ks < 4; ks++) {
            A0a[ks][0] = *(const float4*)(p0 + ks * 32);
            A0a[ks][1] = *(const float4*)(p0 + ks * 32 + 4);
            A0b[ks][0] = *(const float4*)(p1 + ks * 32);
            A0b[ks][1] = *(const float4*)(p1 + ks * 32 + 4);
        }
    }
    if (t1 < T) {
        const float* p0 = A + (size_t)min(mb1 + l15, M - 1) * 128 + lhi * 8;
        const float* p1 = A + (size_t)min(mb1 + 16 + l15, M - 1) * 128 + lhi * 8;
        #pragma unroll
        for (int ks = 0; ks < 4; ks++) {
            A1a[ks][0] = *(const float4*)(p0 + ks * 32);
            A1a[ks][1] = *(const float4*)(p0 + ks * 32 + 4);
            A1b[ks][0] = *(const float4*)(p1 + ks * 32);
            A1b[ks][1] = *(const float4*)(p1 + ks * 32 + 4);
        }
    }

    float alv[8], arv[8];
    #pragma unroll
    for (int n = 0; n < 8; n++) { alv[n] = alp[n * 16 + l15]; arv[n] = arp[n * 16 + l15]; }

    __syncthreads();

    auto do_tile = [&](int mb, const float4 (&Aa)[4][2], const float4 (&Ab)[4][2]) {
        f32x4 acc[2][8];
        #pragma unroll
        for (int f = 0; f < 2; f++)
            #pragma unroll
            for (int n = 0; n < 8; n++) acc[f][n] = (f32x4){0.f, 0.f, 0.f, 0.f};

        #pragma unroll
        for (int ks = 0; ks < 4; ks++) {
            float av[8];
            bf16x8 a0h, a0l, a1h, a1l;
            *(float4*)(av)     = Aa[ks][0];
            *(float4*)(av + 4) = Aa[ks][1];
            #pragma unroll
            for (int j = 0; j < 8; j++) {
                unsigned short h = f2bf_rtne(av[j]);
                a0h[j] = (short)h;
                a0l[j] = (short)f2bf_rtne(av[j] - __uint_as_float((unsigned)h << 16));
            }
            *(float4*)(av)     = Ab[ks][0];
            *(float4*)(av + 4) = Ab[ks][1];
            #pragma unroll
            for (int j = 0; j < 8; j++) {
                unsigned short h = f2bf_rtne(av[j]);
                a1h[j] = (short)h;
                a1l[j] = (short)f2bf_rtne(av[j] - __uint_as_float((unsigned)h << 16));
            }
            const bf16x8* bsv = (const bf16x8*)&Bs[ks][0][0][0];
            #pragma unroll
            for (int n = 0; n < 8; n++) {
                bf16x8 bhv = bsv[(2 * n) * 64 + lane];
                bf16x8 blv = bsv[(2 * n + 1) * 64 + lane];
                acc[0][n] = __builtin_amdgcn_mfma_f32_16x16x32_bf16(a0h, bhv, acc[0][n], 0, 0, 0);
                acc[1][n] = __builtin_amdgcn_mfma_f32_16x16x32_bf16(a1h, bhv, acc[1][n], 0, 0, 0);
                acc[0][n] = __builtin_amdgcn_mfma_f32_16x16x32_bf16(a0l, bhv, acc[0][n], 0, 0, 0);
                acc[1][n] = __builtin_amdgcn_mfma_f32_16x16x32_bf16(a1l, bhv, acc[1][n], 0, 0, 0);
                acc[0][n] = __builtin_amdgcn_mfma_f32_16x16x32_bf16(a0h, blv, acc[0][n], 0, 0, 0);
                acc[1][n] = __builtin_amdgcn_mfma_f32_16x16x32_bf16(a1h, blv, acc[1][n], 0, 0, 0);
            }
        }

        // epilogue: C store + fused per-head el/er (D layout: row=(lane>>4)*4+i, col=lane&15)
        #pragma unroll
        for (int f = 0; f < 2; f++) {
            #pragma unroll
            for (int i = 0; i < 4; i++) {
                int r = mb + f * 16 + lhi * 4 + i;
                bool ok = (r < M);
                if (ok) {
                    #pragma unroll
                    for (int n = 0; n < 8; n++)
                        C[(size_t)r * 128 + n * 16 + l15] = acc[f][n][i];
                }
                float ph[4], qh[4];
                #pragma unroll
                for (int h = 0; h < 4; h++) {
                    ph[h] = acc[f][2 * h][i] * alv[2 * h] + acc[f][2 * h + 1][i] * alv[2 * h + 1];
                    qh[h] = acc[f][2 * h][i] * arv[2 * h] + acc[f][2 * h + 1][i] * arv[2 * h + 1];
                }
                #pragma unroll
                for (int off = 1; off < 16; off <<= 1) {
                    #pragma unroll
                    for (int h = 0; h < 4; h++) {
                        ph[h] += __shfl_xor(ph[h], off);
                        qh[h] += __shfl_xor(qh[h], off);
                    }
                }
                if (ok && l15 < 8) {
                    if (l15 < 4) {
                        float v = (l15 == 0) ? ph[0] : (l15 == 1) ? ph[1] : (l15 == 2) ? ph[2] : ph[3];
                        el[(size_t)r * 4 + l15] = v;
                    } else {
                        int h = l15 - 4;
                        float v = (h == 0) ? qh[0] : (h == 1) ? qh[1] : (h == 2) ? qh[2] : qh[3];
                        er[(size_t)r * 4 + h] = v;
                    }
                }
            }
        }
    };

    do_tile(mb0, A0a, A0b);
    if (t1 < T) do_tile(mb1, A1a, A1b);
}

// ---------------- per-node aggregate (inline edge weights) + bias + ELU ----------------
__global__ __launch_bounds__(256) void aggregate_k(const float* __restrict__ feat, const float* __restrict__ el,
                                                   const float* __restrict__ er, const int* __restrict__ rowptr,
                                                   const int* __restrict__ csrc, const float* __restrict__ bias,
                                                   float* __restrict__ out, int n) {
    int wid = threadIdx.x >> 6;
    int lane = threadIdx.x & 63;
    int node = blockIdx.x * 4 + wid;
    if (node >= n) return;
    int h = lane >> 4;
    int p0 = rowptr[node], p1 = rowptr[node + 1];
    float erv = er[(size_t)node * 4 + h];
    float2 b2 = *(const float2*)(bias + lane * 2);
    float lsum = 0.f, a0 = 0.f, a1 = 0.f;
    int p = p0;
    for (; p + 8 <= p1; p += 8) {
        int s[8];
        float e[8];
        float2 f[8];
        #pragma unroll
        for (int q = 0; q < 8; q++) s[q] = csrc[p + q];
        #pragma unroll
        for (int q = 0; q < 8; q++) e[q] = el[(size_t)s[q] * 4 + h] + erv;
        #pragma unroll
        for (int q = 0; q < 8; q++) f[q] = *(const float2*)(feat + (size_t)s[q] * 128 + lane * 2);
        #pragma unroll
        for (int q = 0; q < 8; q++) {
            float eq = (e[q] > 0.f) ? e[q] : 0.2f * e[q];
            float w = __expf(eq);
            lsum += w;
            a0 += w * f[q].x;
            a1 += w * f[q].y;
        }
    }
    for (; p + 4 <= p1; p += 4) {
        int s0 = csrc[p], s1 = csrc[p + 1], s2 = csrc[p + 2], s3 = csrc[p + 3];
        float e0 = el[(size_t)s0 * 4 + h] + erv;
        float e1 = el[(size_t)s1 * 4 + h] + erv;
        float e2 = el[(size_t)s2 * 4 + h] + erv;
        float e3 = el[(size_t)s3 * 4 + h] + erv;
        e0 = (e0 > 0.f) ? e0 : 0.2f * e0;
        e1 = (e1 > 0.f) ? e1 : 0.2f * e1;
        e2 = (e2 > 0.f) ? e2 : 0.2f * e2;
        e3 = (e3 > 0.f) ? e3 : 0.2f * e3;
        float2 f0 = *(const float2*)(feat + (size_t)s0 * 128 + lane * 2);
        float2 f1 = *(const float2*)(feat + (size_t)s1 * 128 + lane * 2);
        float2 f2 = *(const float2*)(feat + (size_t)s2 * 128 + lane * 2);
        float2 f3 = *(const float2*)(feat + (size_t)s3 * 128 + lane * 2);
        float w0 = __expf(e0), w1 = __expf(e1), w2 = __expf(e2), w3 = __expf(e3);
        lsum += (w0 + w1) + (w2 + w3);
        a0 += w0 * f0.x + w1 * f1.x + w2 * f2.x + w3 * f3.x;
        a1 += w0 * f0.y + w1 * f1.y + w2 * f2.y + w3 * f3.y;
    }
    for (; p < p1; ++p) {
        int s = csrc[p];
        float e = el[(size_t)s * 4 + h] + erv;
        e = (e > 0.f) ? e : 0.2f * e;
        float w = __expf(e);
        float2 f = *(const float2*)(feat + (size_t)s * 128 + lane * 2);
        lsum += w;
        a0 += w * f.x;
        a1 += w * f.y;
    }
    float inv = 1.f / fmaxf(lsum, 1e-9f);
    float v0 = a0 * inv + b2.x;
    float v1 = a1 * inv + b2.y;
    v0 = (v0 > 0.f) ? v0 : expm1f(v0);
    v1 = (v1 > 0.f) ? v1 : expm1f(v1);
    *(float2*)(out + (size_t)node * 128 + lane * 2) = make_float2(v0, v1);
}

// ---------------- projection: hp[N,32] = h[N,128] @ Wp[128,32] + bp ----------------
__global__ __launch_bounds__(256) void proj_k(const float* __restrict__ h, const float* __restrict__ Wp,
                                              const float* __restrict__ bp, float* __restrict__ hp, int n) {
    __shared__ float Ws[128 * 32];
    __shared__ float Hs[32][132];
    int tid = threadIdx.x;
    for (int i = tid; i < 4096; i += 256) Ws[i] = Wp[i];
    int n0 = blockIdx.x * 32;
    for (int i = tid; i < 1024; i += 256) {
        int r = i >> 5, c4 = i & 31;
        int node = n0 + r;
        float4 v = (node < n) ? *(const float4*)(h + (size_t)node * 128 + c4 * 4)
                              : make_float4(0.f, 0.f, 0.f, 0.f);
        *(float4*)&Hs[r][c4 * 4] = v;
    }
    __syncthreads();
    int r = tid >> 3;
    int node = n0 + r;
    int j0 = (tid & 7) * 4;
    if (node < n) {
        float a0 = bp[j0], a1 = bp[j0 + 1], a2 = bp[j0 + 2], a3 = bp[j0 + 3];
        #pragma unroll
        for (int k = 0; k < 128; k++) {
            float av = Hs[r][k];
            float4 w = *(const float4*)&Ws[k * 32 + j0];
            a0 += av * w.x; a1 += av * w.y; a2 += av * w.z; a3 += av * w.w;
        }
        *(float4*)(hp + (size_t)node * 32 + j0) = make_float4(a0, a1, a2, a3);
    }
}

// ---------------- pair predictor MLP ----------------
__global__ __launch_bounds__(256) void predictor_k(const float* __restrict__ hp,
                                                   const int* __restrict__ ps, const int* __restrict__ pd,
                                                   const int* __restrict__ ns, const int* __restrict__ nd,
                                                   const float* __restrict__ Wq1, const float* __restrict__ bq1,
                                                   const float* __restrict__ Wq2, const float* __restrict__ bq2,
                                                   const float* __restrict__ Wq3, const float* __restrict__ bq3,
                                                   float* __restrict__ out, int P) {
    __shared__ float w1[1024], w2[1024], w3[32], b1[32], b2[32];
    int tid = threadIdx.x;
    for (int i = tid; i < 1024; i += 256) { w1[i] = Wq1[i]; w2[i] = Wq2[i]; }
    if (tid < 32) { w3[tid] = Wq3[tid]; b1[tid] = bq1[tid]; b2[tid] = bq2[tid]; }
    __syncthreads();
    int gid = blockIdx.x * 256 + tid;
    if (gid >= 2 * P) return;
    int i = (gid < P) ? gid : gid - P;
    int a = (gid < P) ? ps[i] : ns[i];
    int b = (gid < P) ? pd[i] : nd[i];
    float z[32];
    const float4* ha = (const float4*)(hp + (size_t)a * 32);
    const float4* hb = (const float4*)(hp + (size_t)b * 32);
    #pragma unroll
    for (int q = 0; q < 8; q++) {
        float4 x = ha[q], y = hb[q];
        z[q * 4 + 0] = x.x * y.x; z[q * 4 + 1] = x.y * y.y;
        z[q * 4 + 2] = x.z * y.z; z[q * 4 + 3] = x.w * y.w;
    }
    float z1[32];
    #pragma unroll
    for (int j = 0; j < 32; j++) {
        float s = b1[j];
        #pragma unroll
        for (int k = 0; k < 32; k++) s += z[k] * w1[k * 32 + j];
        z1[j] = fmaxf(s, 0.f);
    }
    #pragma unroll
    for (int j = 0; j < 32; j++) {
        float s = b2[j];
        #pragma unroll
        for (int k = 0; k < 32; k++) s += z1[k] * w2[k * 32 + j];
        z[j] = fmaxf(s, 0.f);
    }
    float s3 = bq3[0];
    #pragma unroll
    for (int j = 0; j < 32; j++) s3 += z[j] * w3[j];
    out[gid] = s3;
}

// ---------------- launch ----------------
extern "C" void kernel_launch(void* const* d_in, const int* in_sizes, int n_in,
                              void* d_out, int out_size, void* d_ws, size_t ws_size,
                              hipStream_t stream) {
    const float* x   = (const float*)d_in[0];
    const int* src   = (const int*)d_in[1];
    const int* dst   = (const int*)d_in[2];
    const int* psrc  = (const int*)d_in[3];
    const int* pdst  = (const int*)d_in[4];
    const int* nsrc  = (const int*)d_in[5];
    const int* ndst  = (const int*)d_in[6];
    const float* W[3]  = { (const float*)d_in[7],  (const float*)d_in[11], (const float*)d_in[15] };
    const float* al[3] = { (const float*)d_in[8],  (const float*)d_in[12], (const float*)d_in[16] };
    const float* ar[3] = { (const float*)d_in[9],  (const float*)d_in[13], (const float*)d_in[17] };
    const float* bb[3] = { (const float*)d_in[10], (const float*)d_in[14], (const float*)d_in[18] };
    const float* Wp  = (const float*)d_in[19];
    const float* bp  = (const float*)d_in[20];
    const float* Wq1 = (const float*)d_in[21];
    const float* bq1 = (const float*)d_in[22];
    const float* Wq2 = (const float*)d_in[23];
    const float* bq2 = (const float*)d_in[24];
    const float* Wq3 = (const float*)d_in[25];
    const float* bq3 = (const float*)d_in[26];
    float* out = (float*)d_out;

    const int N = in_sizes[0] / 128;
    const int E = in_sizes[1];
    const int P = in_sizes[3];

    size_t off = 0;
    auto alloc = [&](size_t bytes) {
        void* p = (char*)d_ws + off;
        off += (bytes + 255) & ~(size_t)255;
        return p;
    };
    float* bufF  = (float*)alloc((size_t)N * 128 * 4);
    float* bufH  = (float*)alloc((size_t)N * 128 * 4);
    float* elA   = (float*)alloc((size_t)N * 4 * 4);
    float* erA   = (float*)alloc((size_t)N * 4 * 4);
    float* hp    = (float*)alloc((size_t)N * 32 * 4);
    int* rowptr  = (int*)alloc((size_t)(N + 1) * 4);
    int* cursor  = (int*)alloc((size_t)(N + 1) * 4);
    int* csrc    = (int*)alloc((size_t)E * 4);
    int* deg     = (int*)alloc((size_t)N * 4);
    int* bsum    = (int*)alloc(1024 * 4);
    unsigned short* Bp = (unsigned short*)alloc(32768 * 2);
    (void)ws_size;

    const int NB_E4 = (E / 4 + 255) / 256;
    const int NB_N = (N + 255) / 256;

    hipMemsetAsync(deg, 0, (size_t)N * 4, stream);

    hist_k<<<NB_E4, 256, 0, stream>>>(dst, deg, E);
    scan1_k<<<NB_N, 256, 0, stream>>>(deg, rowptr, bsum, N);
    scan2_k<<<1, 512, 0, stream>>>(bsum, NB_N);
    scan3_k<<<NB_N, 256, 0, stream>>>(rowptr, cursor, bsum, N);
    fill_k<<<NB_E4, 256, 0, stream>>>(src, dst, cursor, csrc, E);

    const int T = (N + 127) / 128;
    const int GEMM_B = (T + 1) / 2 < 512 ? (T + 1) / 2 : 512;
    const float* hin = x;
    for (int l = 0; l < 3; l++) {
        wconv_k<<<64, 256, 0, stream>>>(W[l], Bp);
        gemm_mfma_k<<<GEMM_B, 256, 0, stream>>>(hin, Bp, al[l], ar[l], bufF, elA, erA, N, T);
        aggregate_k<<<(N + 3) / 4, 256, 0, stream>>>(bufF, elA, erA, rowptr, csrc, bb[l], bufH, N);
        hin = bufH;
    }
    proj_k<<<(N + 31) / 32, 256, 0, stream>>>(bufH, Wp, bp, hp, N);
    predictor_k<<<(2 * P + 255) / 256, 256, 0, stream>>>(hp, psrc, pdst, nsrc, ndst,
                                                         Wq1, bq1, Wq2, bq2, Wq3, bq3, out, P);
}

// Round 13
// 457.282 us; speedup vs baseline: 1.1268x; 1.1268x over previous
//
#include <hip/hip_runtime.h>
#include <math.h>

typedef __attribute__((ext_vector_type(8))) short bf16x8;
typedef __attribute__((ext_vector_type(4))) float f32x4;

__device__ __forceinline__ unsigned short f2bf_rtne(float v) {
    unsigned u = __float_as_uint(v);
    u += 0x7FFFu + ((u >> 16) & 1u);
    return (unsigned short)(u >> 16);
}

// ---------------- CSR build ----------------
__global__ __launch_bounds__(256) void hist_k(const int* __restrict__ dst, int* __restrict__ deg, int e) {
    int i4 = (blockIdx.x * 256 + threadIdx.x) * 4;
    if (i4 + 3 < e) {
        int4 d = *(const int4*)(dst + i4);
        atomicAdd(&deg[d.x], 1);
        atomicAdd(&deg[d.y], 1);
        atomicAdd(&deg[d.z], 1);
        atomicAdd(&deg[d.w], 1);
    } else {
        for (int j = i4; j < e; j++) atomicAdd(&deg[dst[j]], 1);
    }
}

__global__ __launch_bounds__(256) void scan1_k(const int* __restrict__ deg, int* __restrict__ rowptr,
                                               int* __restrict__ bsum, int n) {
    __shared__ int sh[256];
    int tid = threadIdx.x;
    int sid = blockIdx.x * 256 + tid;
    int v = (sid < n) ? deg[sid] : 0;
    sh[tid] = v; __syncthreads();
    for (int off = 1; off < 256; off <<= 1) {
        int t = (tid >= off) ? sh[tid - off] : 0;
        __syncthreads();
        sh[tid] += t;
        __syncthreads();
    }
    if (sid < n) rowptr[sid + 1] = sh[tid];
    if (tid == 255) bsum[blockIdx.x] = sh[255];
}

__global__ __launch_bounds__(512) void scan2_k(int* __restrict__ bsum, int nb) {
    __shared__ int sh[512];
    int tid = threadIdx.x;
    sh[tid] = (tid < nb) ? bsum[tid] : 0;
    __syncthreads();
    for (int off = 1; off < 512; off <<= 1) {
        int t = (tid >= off) ? sh[tid - off] : 0;
        __syncthreads();
        sh[tid] += t;
        __syncthreads();
    }
    if (tid < nb) bsum[tid] = sh[tid];
}

// finalizes rowptr AND initializes cursor = rowptr (fill uses cursor directly)
__global__ __launch_bounds__(256) void scan3_k(int* __restrict__ rowptr, int* __restrict__ cursor,
                                               const int* __restrict__ bsum, int n) {
    int sid = blockIdx.x * 256 + threadIdx.x;
    if (sid == 0) { rowptr[0] = 0; cursor[0] = 0; }
    if (sid < n) {
        int v = rowptr[sid + 1];
        if (blockIdx.x > 0) v += bsum[blockIdx.x - 1];
        rowptr[sid + 1] = v;
        cursor[sid + 1] = v;
    }
}

__global__ __launch_bounds__(256) void fill_k(const int* __restrict__ src, const int* __restrict__ dst,
                                              int* __restrict__ cursor, int* __restrict__ csrc, int e) {
    int i4 = (blockIdx.x * 256 + threadIdx.x) * 4;
    if (i4 + 3 < e) {
        int4 s = *(const int4*)(src + i4);
        int4 d = *(const int4*)(dst + i4);
        int p0 = atomicAdd(&cursor[d.x], 1);
        int p1 = atomicAdd(&cursor[d.y], 1);
        int p2 = atomicAdd(&cursor[d.z], 1);
        int p3 = atomicAdd(&cursor[d.w], 1);
        csrc[p0] = s.x; csrc[p1] = s.y; csrc[p2] = s.z; csrc[p3] = s.w;
    } else {
        for (int j = i4; j < e; j++) {
            int pos = atomicAdd(&cursor[dst[j]], 1);
            csrc[pos] = src[j];
        }
    }
}

// ---------------- W -> packed hi/lo bf16 MFMA fragments ----------------
// Bp layout: [ks=4][slot=16][lane=64][j=8] shorts, slot = 2n (hi) / 2n+1 (lo).
__global__ __launch_bounds__(256) void wconv_k(const float* __restrict__ W, unsigned short* __restrict__ Bp) {
    int idx = blockIdx.x * 256 + threadIdx.x;    // 0..16383 = (k, ncol)
    int k = idx >> 7, nc = idx & 127;
    float v = W[idx];
    unsigned short h = f2bf_rtne(v);
    float hf = __uint_as_float((unsigned)h << 16);
    unsigned short lo = f2bf_rtne(v - hf);
    int n = nc >> 4, l15 = nc & 15, ks = k >> 5, lhi = (k >> 3) & 3, j = k & 7;
    int lanei = lhi * 16 + l15;
    Bp[(((ks * 16 + 2 * n) * 64) + lanei) * 8 + j] = h;
    Bp[(((ks * 16 + 2 * n + 1) * 64) + lanei) * 8 + j] = lo;
}

// ---------------- split-bf16 MFMA GEMM: C[M,128] = A @ W, fused el/er ----------------
// A*W ~= Ah*Wh + Ah*Wl + Al*Wh. Round-13: 512 threads / 8 waves per block, each wave
// owns 16 rows (1 M-frag x 8 N-frags). Same 64KB single-buffer LDS (2 blocks/CU) but
// 16 waves/CU resident (4/SIMD) -- double round-11's occupancy, the stuck counter.
// Round-12 two-tile (grid 391 < 512 slots -> 1 block on most CUs, 100us) reverted.
// K-loop reg+LDS only (round-8 lesson); all A hoisted pre-barrier.
__global__ __launch_bounds__(512) void gemm_mfma_k(const float* __restrict__ A,
        const unsigned short* __restrict__ Bp,
        const float* __restrict__ alp, const float* __restrict__ arp,
        float* __restrict__ C, float* __restrict__ el, float* __restrict__ er, int M) {
    __shared__ short Bs[4][16][64][8];   // 64 KB
    int tid = threadIdx.x;
    int wv = tid >> 6, lane = tid & 63;
    int l15 = lane & 15, lhi = lane >> 4;
    int mb = blockIdx.x * 128 + wv * 16;

    // hoist wave's A rows (16 rows x full K): 8 independent float4s in flight
    const float* a0p = A + (size_t)min(mb + l15, M - 1) * 128 + lhi * 8;
    float4 A0[4][2];
    #pragma unroll
    for (int ks = 0; ks < 4; ks++) {
        A0[ks][0] = *(const float4*)(a0p + ks * 32);
        A0[ks][1] = *(const float4*)(a0p + ks * 32 + 4);
    }

    // stage packed B (hi+lo, full K = 64KB): pure linear copy, 8 float4/thread
    {
        const float4* g = (const float4*)Bp;
        float4* s = (float4*)&Bs[0][0][0][0];
        #pragma unroll
        for (int p = 0; p < 8; p++) s[tid + p * 512] = g[tid + p * 512];
    }

    f32x4 acc[8];
    #pragma unroll
    for (int n = 0; n < 8; n++) acc[n] = (f32x4){0.f, 0.f, 0.f, 0.f};

    float alv[8], arv[8];
    #pragma unroll
    for (int n = 0; n < 8; n++) { alv[n] = alp[n * 16 + l15]; arv[n] = arp[n * 16 + l15]; }

    __syncthreads();

    #pragma unroll
    for (int ks = 0; ks < 4; ks++) {
        float av[8];
        bf16x8 a0h, a0l;
        *(float4*)(av)     = A0[ks][0];
        *(float4*)(av + 4) = A0[ks][1];
        #pragma unroll
        for (int j = 0; j < 8; j++) {
            unsigned short h = f2bf_rtne(av[j]);
            a0h[j] = (short)h;
            a0l[j] = (short)f2bf_rtne(av[j] - __uint_as_float((unsigned)h << 16));
        }
        const bf16x8* bsv = (const bf16x8*)&Bs[ks][0][0][0];
        #pragma unroll
        for (int n = 0; n < 8; n++) {
            bf16x8 bhv = bsv[(2 * n) * 64 + lane];
            bf16x8 blv = bsv[(2 * n + 1) * 64 + lane];
            acc[n] = __builtin_amdgcn_mfma_f32_16x16x32_bf16(a0h, bhv, acc[n], 0, 0, 0);
            acc[n] = __builtin_amdgcn_mfma_f32_16x16x32_bf16(a0l, bhv, acc[n], 0, 0, 0);
            acc[n] = __builtin_amdgcn_mfma_f32_16x16x32_bf16(a0h, blv, acc[n], 0, 0, 0);
        }
    }

    // epilogue: C store + fused per-head el/er (D layout: row=(lane>>4)*4+i, col=lane&15)
    #pragma unroll
    for (int i = 0; i < 4; i++) {
        int r = mb + lhi * 4 + i;
        bool ok = (r < M);
        if (ok) {
            #pragma unroll
            for (int n = 0; n < 8; n++)
                C[(size_t)r * 128 + n * 16 + l15] = acc[n][i];
        }
        float ph[4], qh[4];
        #pragma unroll
        for (int h = 0; h < 4; h++) {
            ph[h] = acc[2 * h][i] * alv[2 * h] + acc[2 * h + 1][i] * alv[2 * h + 1];
            qh[h] = acc[2 * h][i] * arv[2 * h] + acc[2 * h + 1][i] * arv[2 * h + 1];
        }
        #pragma unroll
        for (int off = 1; off < 16; off <<= 1) {
            #pragma unroll
            for (int h = 0; h < 4; h++) {
                ph[h] += __shfl_xor(ph[h], off);
                qh[h] += __shfl_xor(qh[h], off);
            }
        }
        if (ok && l15 < 8) {
            if (l15 < 4) {
                float v = (l15 == 0) ? ph[0] : (l15 == 1) ? ph[1] : (l15 == 2) ? ph[2] : ph[3];
                el[(size_t)r * 4 + l15] = v;
            } else {
                int h = l15 - 4;
                float v = (h == 0) ? qh[0] : (h == 1) ? qh[1] : (h == 2) ? qh[2] : qh[3];
                er[(size_t)r * 4 + h] = v;
            }
        }
    }
}

// ---------------- per-node aggregate (inline edge weights) + bias + ELU ----------------
__global__ __launch_bounds__(256) void aggregate_k(const float* __restrict__ feat, const float* __restrict__ el,
                                                   const float* __restrict__ er, const int* __restrict__ rowptr,
                                                   const int* __restrict__ csrc, const float* __restrict__ bias,
                                                   float* __restrict__ out, int n) {
    int wid = threadIdx.x >> 6;
    int lane = threadIdx.x & 63;
    int node = blockIdx.x * 4 + wid;
    if (node >= n) return;
    int h = lane >> 4;
    int p0 = rowptr[node], p1 = rowptr[node + 1];
    float erv = er[(size_t)node * 4 + h];
    float2 b2 = *(const float2*)(bias + lane * 2);
    float lsum = 0.f, a0 = 0.f, a1 = 0.f;
    int p = p0;
    for (; p + 8 <= p1; p += 8) {
        int s[8];
        float e[8];
        float2 f[8];
        #pragma unroll
        for (int q = 0; q < 8; q++) s[q] = csrc[p + q];
        #pragma unroll
        for (int q = 0; q < 8; q++) e[q] = el[(size_t)s[q] * 4 + h] + erv;
        #pragma unroll
        for (int q = 0; q < 8; q++) f[q] = *(const float2*)(feat + (size_t)s[q] * 128 + lane * 2);
        #pragma unroll
        for (int q = 0; q < 8; q++) {
            float eq = (e[q] > 0.f) ? e[q] : 0.2f * e[q];
            float w = __expf(eq);
            lsum += w;
            a0 += w * f[q].x;
            a1 += w * f[q].y;
        }
    }
    for (; p + 4 <= p1; p += 4) {
        int s0 = csrc[p], s1 = csrc[p + 1], s2 = csrc[p + 2], s3 = csrc[p + 3];
        float e0 = el[(size_t)s0 * 4 + h] + erv;
        float e1 = el[(size_t)s1 * 4 + h] + erv;
        float e2 = el[(size_t)s2 * 4 + h] + erv;
        float e3 = el[(size_t)s3 * 4 + h] + erv;
        e0 = (e0 > 0.f) ? e0 : 0.2f * e0;
        e1 = (e1 > 0.f) ? e1 : 0.2f * e1;
        e2 = (e2 > 0.f) ? e2 : 0.2f * e2;
        e3 = (e3 > 0.f) ? e3 : 0.2f * e3;
        float2 f0 = *(const float2*)(feat + (size_t)s0 * 128 + lane * 2);
        float2 f1 = *(const float2*)(feat + (size_t)s1 * 128 + lane * 2);
        float2 f2 = *(const float2*)(feat + (size_t)s2 * 128 + lane * 2);
        float2 f3 = *(const float2*)(feat + (size_t)s3 * 128 + lane * 2);
        float w0 = __expf(e0), w1 = __expf(e1), w2 = __expf(e2), w3 = __expf(e3);
        lsum += (w0 + w1) + (w2 + w3);
        a0 += w0 * f0.x + w1 * f1.x + w2 * f2.x + w3 * f3.x;
        a1 += w0 * f0.y + w1 * f1.y + w2 * f2.y + w3 * f3.y;
    }
    for (; p < p1; ++p) {
        int s = csrc[p];
        float e = el[(size_t)s * 4 + h] + erv;
        e = (e > 0.f) ? e : 0.2f * e;
        float w = __expf(e);
        float2 f = *(const float2*)(feat + (size_t)s * 128 + lane * 2);
        lsum += w;
        a0 += w * f.x;
        a1 += w * f.y;
    }
    float inv = 1.f / fmaxf(lsum, 1e-9f);
    float v0 = a0 * inv + b2.x;
    float v1 = a1 * inv + b2.y;
    v0 = (v0 > 0.f) ? v0 : expm1f(v0);
    v1 = (v1 > 0.f) ? v1 : expm1f(v1);
    *(float2*)(out + (size_t)node * 128 + lane * 2) = make_float2(v0, v1);
}

// ---------------- projection: hp[N,32] = h[N,128] @ Wp[128,32] + bp ----------------
__global__ __launch_bounds__(256) void proj_k(const float* __restrict__ h, const float* __restrict__ Wp,
                                              const float* __restrict__ bp, float* __restrict__ hp, int n) {
    __shared__ float Ws[128 * 32];
    __shared__ float Hs[32][132];
    int tid = threadIdx.x;
    for (int i = tid; i < 4096; i += 256) Ws[i] = Wp[i];
    int n0 = blockIdx.x * 32;
    for (int i = tid; i < 1024; i += 256) {
        int r = i >> 5, c4 = i & 31;
        int node = n0 + r;
        float4 v = (node < n) ? *(const float4*)(h + (size_t)node * 128 + c4 * 4)
                              : make_float4(0.f, 0.f, 0.f, 0.f);
        *(float4*)&Hs[r][c4 * 4] = v;
    }
    __syncthreads();
    int r = tid >> 3;
    int node = n0 + r;
    int j0 = (tid & 7) * 4;
    if (node < n) {
        float a0 = bp[j0], a1 = bp[j0 + 1], a2 = bp[j0 + 2], a3 = bp[j0 + 3];
        #pragma unroll
        for (int k = 0; k < 128; k++) {
            float av = Hs[r][k];
            float4 w = *(const float4*)&Ws[k * 32 + j0];
            a0 += av * w.x; a1 += av * w.y; a2 += av * w.z; a3 += av * w.w;
        }
        *(float4*)(hp + (size_t)node * 32 + j0) = make_float4(a0, a1, a2, a3);
    }
}

// ---------------- pair predictor MLP ----------------
__global__ __launch_bounds__(256) void predictor_k(const float* __restrict__ hp,
                                                   const int* __restrict__ ps, const int* __restrict__ pd,
                                                   const int* __restrict__ ns, const int* __restrict__ nd,
                                                   const float* __restrict__ Wq1, const float* __restrict__ bq1,
                                                   const float* __restrict__ Wq2, const float* __restrict__ bq2,
                                                   const float* __restrict__ Wq3, const float* __restrict__ bq3,
                                                   float* __restrict__ out, int P) {
    __shared__ float w1[1024], w2[1024], w3[32], b1[32], b2[32];
    int tid = threadIdx.x;
    for (int i = tid; i < 1024; i += 256) { w1[i] = Wq1[i]; w2[i] = Wq2[i]; }
    if (tid < 32) { w3[tid] = Wq3[tid]; b1[tid] = bq1[tid]; b2[tid] = bq2[tid]; }
    __syncthreads();
    int gid = blockIdx.x * 256 + tid;
    if (gid >= 2 * P) return;
    int i = (gid < P) ? gid : gid - P;
    int a = (gid < P) ? ps[i] : ns[i];
    int b = (gid < P) ? pd[i] : nd[i];
    float z[32];
    const float4* ha = (const float4*)(hp + (size_t)a * 32);
    const float4* hb = (const float4*)(hp + (size_t)b * 32);
    #pragma unroll
    for (int q = 0; q < 8; q++) {
        float4 x = ha[q], y = hb[q];
        z[q * 4 + 0] = x.x * y.x; z[q * 4 + 1] = x.y * y.y;
        z[q * 4 + 2] = x.z * y.z; z[q * 4 + 3] = x.w * y.w;
    }
    float z1[32];
    #pragma unroll
    for (int j = 0; j < 32; j++) {
        float s = b1[j];
        #pragma unroll
        for (int k = 0; k < 32; k++) s += z[k] * w1[k * 32 + j];
        z1[j] = fmaxf(s, 0.f);
    }
    #pragma unroll
    for (int j = 0; j < 32; j++) {
        float s = b2[j];
        #pragma unroll
        for (int k = 0; k < 32; k++) s += z1[k] * w2[k * 32 + j];
        z[j] = fmaxf(s, 0.f);
    }
    float s3 = bq3[0];
    #pragma unroll
    for (int j = 0; j < 32; j++) s3 += z[j] * w3[j];
    out[gid] = s3;
}

// ---------------- launch ----------------
extern "C" void kernel_launch(void* const* d_in, const int* in_sizes, int n_in,
                              void* d_out, int out_size, void* d_ws, size_t ws_size,
                              hipStream_t stream) {
    const float* x   = (const float*)d_in[0];
    const int* src   = (const int*)d_in[1];
    const int* dst   = (const int*)d_in[2];
    const int* psrc  = (const int*)d_in[3];
    const int* pdst  = (const int*)d_in[4];
    const int* nsrc  = (const int*)d_in[5];
    const int* ndst  = (const int*)d_in[6];
    const float* W[3]  = { (const float*)d_in[7],  (const float*)d_in[11], (const float*)d_in[15] };
    const float* al[3] = { (const float*)d_in[8],  (const float*)d_in[12], (const float*)d_in[16] };
    const float* ar[3] = { (const float*)d_in[9],  (const float*)d_in[13], (const float*)d_in[17] };
    const float* bb[3] = { (const float*)d_in[10], (const float*)d_in[14], (const float*)d_in[18] };
    const float* Wp  = (const float*)d_in[19];
    const float* bp  = (const float*)d_in[20];
    const float* Wq1 = (const float*)d_in[21];
    const float* bq1 = (const float*)d_in[22];
    const float* Wq2 = (const float*)d_in[23];
    const float* bq2 = (const float*)d_in[24];
    const float* Wq3 = (const float*)d_in[25];
    const float* bq3 = (const float*)d_in[26];
    float* out = (float*)d_out;

    const int N = in_sizes[0] / 128;
    const int E = in_sizes[1];
    const int P = in_sizes[3];

    size_t off = 0;
    auto alloc = [&](size_t bytes) {
        void* p = (char*)d_ws + off;
        off += (bytes + 255) & ~(size_t)255;
        return p;
    };
    float* bufF  = (float*)alloc((size_t)N * 128 * 4);
    float* bufH  = (float*)alloc((size_t)N * 128 * 4);
    float* elA   = (float*)alloc((size_t)N * 4 * 4);
    float* erA   = (float*)alloc((size_t)N * 4 * 4);
    float* hp    = (float*)alloc((size_t)N * 32 * 4);
    int* rowptr  = (int*)alloc((size_t)(N + 1) * 4);
    int* cursor  = (int*)alloc((size_t)(N + 1) * 4);
    int* csrc    = (int*)alloc((size_t)E * 4);
    int* deg     = (int*)alloc((size_t)N * 4);
    int* bsum    = (int*)alloc(1024 * 4);
    unsigned short* Bp = (unsigned short*)alloc(32768 * 2);
    (void)ws_size;

    const int NB_E4 = (E / 4 + 255) / 256;
    const int NB_N = (N + 255) / 256;

    hipMemsetAsync(deg, 0, (size_t)N * 4, stream);

    hist_k<<<NB_E4, 256, 0, stream>>>(dst, deg, E);
    scan1_k<<<NB_N, 256, 0, stream>>>(deg, rowptr, bsum, N);
    scan2_k<<<1, 512, 0, stream>>>(bsum, NB_N);
    scan3_k<<<NB_N, 256, 0, stream>>>(rowptr, cursor, bsum, N);
    fill_k<<<NB_E4, 256, 0, stream>>>(src, dst, cursor, csrc, E);

    const int GEMM_B = (N + 127) / 128;
    const float* hin = x;
    for (int l = 0; l < 3; l++) {
        wconv_k<<<64, 256, 0, stream>>>(W[l], Bp);
        gemm_mfma_k<<<GEMM_B, 512, 0, stream>>>(hin, Bp, al[l], ar[l], bufF, elA, erA, N);
        aggregate_k<<<(N + 3) / 4, 256, 0, stream>>>(bufF, elA, erA, rowptr, csrc, bb[l], bufH, N);
        hin = bufH;
    }
    proj_k<<<(N + 31) / 32, 256, 0, stream>>>(bufH, Wp, bp, hp, N);
    predictor_k<<<(2 * P + 255) / 256, 256, 0, stream>>>(hp, psrc, pdst, nsrc, ndst,
                                                         Wq1, bq1, Wq2, bq2, Wq3, bq3, out, P);
}

// Round 14
// 452.637 us; speedup vs baseline: 1.1384x; 1.0103x over previous
//
#include <hip/hip_runtime.h>
#include <math.h>

typedef __attribute__((ext_vector_type(8))) short bf16x8;
typedef __attribute__((ext_vector_type(4))) float f32x4;

__device__ __forceinline__ unsigned short f2bf_rtne(float v) {
    unsigned u = __float_as_uint(v);
    u += 0x7FFFu + ((u >> 16) & 1u);
    return (unsigned short)(u >> 16);
}

// ---------------- CSR build ----------------
__global__ __launch_bounds__(256) void hist_k(const int* __restrict__ dst, int* __restrict__ deg, int e) {
    int i4 = (blockIdx.x * 256 + threadIdx.x) * 4;
    if (i4 + 3 < e) {
        int4 d = *(const int4*)(dst + i4);
        atomicAdd(&deg[d.x], 1);
        atomicAdd(&deg[d.y], 1);
        atomicAdd(&deg[d.z], 1);
        atomicAdd(&deg[d.w], 1);
    } else {
        for (int j = i4; j < e; j++) atomicAdd(&deg[dst[j]], 1);
    }
}

__global__ __launch_bounds__(256) void scan1_k(const int* __restrict__ deg, int* __restrict__ rowptr,
                                               int* __restrict__ bsum, int n) {
    __shared__ int sh[256];
    int tid = threadIdx.x;
    int sid = blockIdx.x * 256 + tid;
    int v = (sid < n) ? deg[sid] : 0;
    sh[tid] = v; __syncthreads();
    for (int off = 1; off < 256; off <<= 1) {
        int t = (tid >= off) ? sh[tid - off] : 0;
        __syncthreads();
        sh[tid] += t;
        __syncthreads();
    }
    if (sid < n) rowptr[sid + 1] = sh[tid];
    if (tid == 255) bsum[blockIdx.x] = sh[255];
}

__global__ __launch_bounds__(512) void scan2_k(int* __restrict__ bsum, int nb) {
    __shared__ int sh[512];
    int tid = threadIdx.x;
    sh[tid] = (tid < nb) ? bsum[tid] : 0;
    __syncthreads();
    for (int off = 1; off < 512; off <<= 1) {
        int t = (tid >= off) ? sh[tid - off] : 0;
        __syncthreads();
        sh[tid] += t;
        __syncthreads();
    }
    if (tid < nb) bsum[tid] = sh[tid];
}

// finalizes rowptr AND initializes cursor = rowptr (fill uses cursor directly)
__global__ __launch_bounds__(256) void scan3_k(int* __restrict__ rowptr, int* __restrict__ cursor,
                                               const int* __restrict__ bsum, int n) {
    int sid = blockIdx.x * 256 + threadIdx.x;
    if (sid == 0) { rowptr[0] = 0; cursor[0] = 0; }
    if (sid < n) {
        int v = rowptr[sid + 1];
        if (blockIdx.x > 0) v += bsum[blockIdx.x - 1];
        rowptr[sid + 1] = v;
        cursor[sid + 1] = v;
    }
}

__global__ __launch_bounds__(256) void fill_k(const int* __restrict__ src, const int* __restrict__ dst,
                                              int* __restrict__ cursor, int* __restrict__ csrc, int e) {
    int i4 = (blockIdx.x * 256 + threadIdx.x) * 4;
    if (i4 + 3 < e) {
        int4 s = *(const int4*)(src + i4);
        int4 d = *(const int4*)(dst + i4);
        int p0 = atomicAdd(&cursor[d.x], 1);
        int p1 = atomicAdd(&cursor[d.y], 1);
        int p2 = atomicAdd(&cursor[d.z], 1);
        int p3 = atomicAdd(&cursor[d.w], 1);
        csrc[p0] = s.x; csrc[p1] = s.y; csrc[p2] = s.z; csrc[p3] = s.w;
    } else {
        for (int j = i4; j < e; j++) {
            int pos = atomicAdd(&cursor[dst[j]], 1);
            csrc[pos] = src[j];
        }
    }
}

// ---------------- all 3 W's -> packed hi/lo bf16 MFMA fragments (one launch) ----------------
// Bp layout per layer: [ks=4][slot=16][lane=64][j=8] shorts, slot = 2n (hi) / 2n+1 (lo).
__global__ __launch_bounds__(256) void wconv3_k(const float* __restrict__ W0, const float* __restrict__ W1,
                                                const float* __restrict__ W2, unsigned short* __restrict__ Bp) {
    int gidx = blockIdx.x * 256 + threadIdx.x;   // 0..49151
    int layer = gidx >> 14;
    int idx = gidx & 16383;                      // (k, ncol)
    const float* W = (layer == 0) ? W0 : (layer == 1) ? W1 : W2;
    int k = idx >> 7, nc = idx & 127;
    float v = W[idx];
    unsigned short h = f2bf_rtne(v);
    float hf = __uint_as_float((unsigned)h << 16);
    unsigned short lo = f2bf_rtne(v - hf);
    int n = nc >> 4, l15 = nc & 15, ks = k >> 5, lhi = (k >> 3) & 3, j = k & 7;
    int lanei = lhi * 16 + l15;
    unsigned short* B = Bp + (size_t)layer * 32768;
    B[(((ks * 16 + 2 * n) * 64) + lanei) * 8 + j] = h;
    B[(((ks * 16 + 2 * n + 1) * 64) + lanei) * 8 + j] = lo;
}

// ---------------- split-bf16 MFMA GEMM: C[M,128] = A @ W, fused el/er ----------------
// A*W ~= Ah*Wh + Ah*Wl + Al*Wh. 512 threads / 8 waves, wave owns 16 rows
// (1 M-frag x 8 N-frags of mfma_f32_16x16x32_bf16). 64KB single-buffer LDS,
// 16 waves/CU. Round-14: B staged via global_load_lds width=16 (direct-to-LDS DMA,
// no VGPR round-trip; dest is wave-uniform base + lane*16 -- our copy is exactly
// linear). A hoisted to regs pre-barrier; K-loop reg+LDS only (round-8 lesson).
__global__ __launch_bounds__(512) void gemm_mfma_k(const float* __restrict__ A,
        const unsigned short* __restrict__ Bp,
        const float* __restrict__ alp, const float* __restrict__ arp,
        float* __restrict__ C, float* __restrict__ el, float* __restrict__ er, int M) {
    __shared__ short Bs[4][16][64][8];   // 64 KB
    int tid = threadIdx.x;
    int wv = tid >> 6, lane = tid & 63;
    int l15 = lane & 15, lhi = lane >> 4;
    int mb = blockIdx.x * 128 + wv * 16;

    // stage packed B (hi+lo, full K = 64KB) via direct-to-LDS loads:
    // 8 x (512 lanes x 16B) = 64KB; lds dest = wave-uniform base + lane*16.
    {
        const char* g = (const char*)Bp;
        char* sbase = (char*)&Bs[0][0][0][0];
        #pragma unroll
        for (int p = 0; p < 8; p++) {
            __builtin_amdgcn_global_load_lds(
                (const __attribute__((address_space(1))) unsigned int*)(g + (size_t)(tid + p * 512) * 16),
                (__attribute__((address_space(3))) unsigned int*)(sbase + (wv * 64 + p * 512) * 16),
                16, 0, 0);
        }
    }

    // hoist wave's A rows (16 rows x full K): 8 independent float4s in flight
    const float* a0p = A + (size_t)min(mb + l15, M - 1) * 128 + lhi * 8;
    float4 A0[4][2];
    #pragma unroll
    for (int ks = 0; ks < 4; ks++) {
        A0[ks][0] = *(const float4*)(a0p + ks * 32);
        A0[ks][1] = *(const float4*)(a0p + ks * 32 + 4);
    }

    f32x4 acc[8];
    #pragma unroll
    for (int n = 0; n < 8; n++) acc[n] = (f32x4){0.f, 0.f, 0.f, 0.f};

    float alv[8], arv[8];
    #pragma unroll
    for (int n = 0; n < 8; n++) { alv[n] = alp[n * 16 + l15]; arv[n] = arp[n * 16 + l15]; }

    __syncthreads();

    #pragma unroll
    for (int ks = 0; ks < 4; ks++) {
        float av[8];
        bf16x8 a0h, a0l;
        *(float4*)(av)     = A0[ks][0];
        *(float4*)(av + 4) = A0[ks][1];
        #pragma unroll
        for (int j = 0; j < 8; j++) {
            unsigned short h = f2bf_rtne(av[j]);
            a0h[j] = (short)h;
            a0l[j] = (short)f2bf_rtne(av[j] - __uint_as_float((unsigned)h << 16));
        }
        const bf16x8* bsv = (const bf16x8*)&Bs[ks][0][0][0];
        #pragma unroll
        for (int n = 0; n < 8; n++) {
            bf16x8 bhv = bsv[(2 * n) * 64 + lane];
            bf16x8 blv = bsv[(2 * n + 1) * 64 + lane];
            acc[n] = __builtin_amdgcn_mfma_f32_16x16x32_bf16(a0h, bhv, acc[n], 0, 0, 0);
            acc[n] = __builtin_amdgcn_mfma_f32_16x16x32_bf16(a0l, bhv, acc[n], 0, 0, 0);
            acc[n] = __builtin_amdgcn_mfma_f32_16x16x32_bf16(a0h, blv, acc[n], 0, 0, 0);
        }
    }

    // epilogue: C store + fused per-head el/er (D layout: row=(lane>>4)*4+i, col=lane&15)
    #pragma unroll
    for (int i = 0; i < 4; i++) {
        int r = mb + lhi * 4 + i;
        bool ok = (r < M);
        if (ok) {
            #pragma unroll
            for (int n = 0; n < 8; n++)
                C[(size_t)r * 128 + n * 16 + l15] = acc[n][i];
        }
        float ph[4], qh[4];
        #pragma unroll
        for (int h = 0; h < 4; h++) {
            ph[h] = acc[2 * h][i] * alv[2 * h] + acc[2 * h + 1][i] * alv[2 * h + 1];
            qh[h] = acc[2 * h][i] * arv[2 * h] + acc[2 * h + 1][i] * arv[2 * h + 1];
        }
        #pragma unroll
        for (int off = 1; off < 16; off <<= 1) {
            #pragma unroll
            for (int h = 0; h < 4; h++) {
                ph[h] += __shfl_xor(ph[h], off);
                qh[h] += __shfl_xor(qh[h], off);
            }
        }
        if (ok && l15 < 8) {
            if (l15 < 4) {
                float v = (l15 == 0) ? ph[0] : (l15 == 1) ? ph[1] : (l15 == 2) ? ph[2] : ph[3];
                el[(size_t)r * 4 + l15] = v;
            } else {
                int h = l15 - 4;
                float v = (h == 0) ? qh[0] : (h == 1) ? qh[1] : (h == 2) ? qh[2] : qh[3];
                er[(size_t)r * 4 + h] = v;
            }
        }
    }
}

// ---------------- per-node aggregate (inline edge weights) + bias + ELU ----------------
__global__ __launch_bounds__(256) void aggregate_k(const float* __restrict__ feat, const float* __restrict__ el,
                                                   const float* __restrict__ er, const int* __restrict__ rowptr,
                                                   const int* __restrict__ csrc, const float* __restrict__ bias,
                                                   float* __restrict__ out, int n) {
    int wid = threadIdx.x >> 6;
    int lane = threadIdx.x & 63;
    int node = blockIdx.x * 4 + wid;
    if (node >= n) return;
    int h = lane >> 4;
    int p0 = rowptr[node], p1 = rowptr[node + 1];
    float erv = er[(size_t)node * 4 + h];
    float2 b2 = *(const float2*)(bias + lane * 2);
    float lsum = 0.f, a0 = 0.f, a1 = 0.f;
    int p = p0;
    for (; p + 8 <= p1; p += 8) {
        int s[8];
        float e[8];
        float2 f[8];
        #pragma unroll
        for (int q = 0; q < 8; q++) s[q] = csrc[p + q];
        #pragma unroll
        for (int q = 0; q < 8; q++) e[q] = el[(size_t)s[q] * 4 + h] + erv;
        #pragma unroll
        for (int q = 0; q < 8; q++) f[q] = *(const float2*)(feat + (size_t)s[q] * 128 + lane * 2);
        #pragma unroll
        for (int q = 0; q < 8; q++) {
            float eq = (e[q] > 0.f) ? e[q] : 0.2f * e[q];
            float w = __expf(eq);
            lsum += w;
            a0 += w * f[q].x;
            a1 += w * f[q].y;
        }
    }
    for (; p + 4 <= p1; p += 4) {
        int s0 = csrc[p], s1 = csrc[p + 1], s2 = csrc[p + 2], s3 = csrc[p + 3];
        float e0 = el[(size_t)s0 * 4 + h] + erv;
        float e1 = el[(size_t)s1 * 4 + h] + erv;
        float e2 = el[(size_t)s2 * 4 + h] + erv;
        float e3 = el[(size_t)s3 * 4 + h] + erv;
        e0 = (e0 > 0.f) ? e0 : 0.2f * e0;
        e1 = (e1 > 0.f) ? e1 : 0.2f * e1;
        e2 = (e2 > 0.f) ? e2 : 0.2f * e2;
        e3 = (e3 > 0.f) ? e3 : 0.2f * e3;
        float2 f0 = *(const float2*)(feat + (size_t)s0 * 128 + lane * 2);
        float2 f1 = *(const float2*)(feat + (size_t)s1 * 128 + lane * 2);
        float2 f2 = *(const float2*)(feat + (size_t)s2 * 128 + lane * 2);
        float2 f3 = *(const float2*)(feat + (size_t)s3 * 128 + lane * 2);
        float w0 = __expf(e0), w1 = __expf(e1), w2 = __expf(e2), w3 = __expf(e3);
        lsum += (w0 + w1) + (w2 + w3);
        a0 += w0 * f0.x + w1 * f1.x + w2 * f2.x + w3 * f3.x;
        a1 += w0 * f0.y + w1 * f1.y + w2 * f2.y + w3 * f3.y;
    }
    for (; p < p1; ++p) {
        int s = csrc[p];
        float e = el[(size_t)s * 4 + h] + erv;
        e = (e > 0.f) ? e : 0.2f * e;
        float w = __expf(e);
        float2 f = *(const float2*)(feat + (size_t)s * 128 + lane * 2);
        lsum += w;
        a0 += w * f.x;
        a1 += w * f.y;
    }
    float inv = 1.f / fmaxf(lsum, 1e-9f);
    float v0 = a0 * inv + b2.x;
    float v1 = a1 * inv + b2.y;
    v0 = (v0 > 0.f) ? v0 : expm1f(v0);
    v1 = (v1 > 0.f) ? v1 : expm1f(v1);
    *(float2*)(out + (size_t)node * 128 + lane * 2) = make_float2(v0, v1);
}

// ---------------- projection: hp[N,32] = h[N,128] @ Wp[128,32] + bp ----------------
__global__ __launch_bounds__(256) void proj_k(const float* __restrict__ h, const float* __restrict__ Wp,
                                              const float* __restrict__ bp, float* __restrict__ hp, int n) {
    __shared__ float Ws[128 * 32];
    __shared__ float Hs[32][132];
    int tid = threadIdx.x;
    for (int i = tid; i < 4096; i += 256) Ws[i] = Wp[i];
    int n0 = blockIdx.x * 32;
    for (int i = tid; i < 1024; i += 256) {
        int r = i >> 5, c4 = i & 31;
        int node = n0 + r;
        float4 v = (node < n) ? *(const float4*)(h + (size_t)node * 128 + c4 * 4)
                              : make_float4(0.f, 0.f, 0.f, 0.f);
        *(float4*)&Hs[r][c4 * 4] = v;
    }
    __syncthreads();
    int r = tid >> 3;
    int node = n0 + r;
    int j0 = (tid & 7) * 4;
    if (node < n) {
        float a0 = bp[j0], a1 = bp[j0 + 1], a2 = bp[j0 + 2], a3 = bp[j0 + 3];
        #pragma unroll
        for (int k = 0; k < 128; k++) {
            float av = Hs[r][k];
            float4 w = *(const float4*)&Ws[k * 32 + j0];
            a0 += av * w.x; a1 += av * w.y; a2 += av * w.z; a3 += av * w.w;
        }
        *(float4*)(hp + (size_t)node * 32 + j0) = make_float4(a0, a1, a2, a3);
    }
}

// ---------------- pair predictor MLP ----------------
__global__ __launch_bounds__(256) void predictor_k(const float* __restrict__ hp,
                                                   const int* __restrict__ ps, const int* __restrict__ pd,
                                                   const int* __restrict__ ns, const int* __restrict__ nd,
                                                   const float* __restrict__ Wq1, const float* __restrict__ bq1,
                                                   const float* __restrict__ Wq2, const float* __restrict__ bq2,
                                                   const float* __restrict__ Wq3, const float* __restrict__ bq3,
                                                   float* __restrict__ out, int P) {
    __shared__ float w1[1024], w2[1024], w3[32], b1[32], b2[32];
    int tid = threadIdx.x;
    for (int i = tid; i < 1024; i += 256) { w1[i] = Wq1[i]; w2[i] = Wq2[i]; }
    if (tid < 32) { w3[tid] = Wq3[tid]; b1[tid] = bq1[tid]; b2[tid] = bq2[tid]; }
    __syncthreads();
    int gid = blockIdx.x * 256 + tid;
    if (gid >= 2 * P) return;
    int i = (gid < P) ? gid : gid - P;
    int a = (gid < P) ? ps[i] : ns[i];
    int b = (gid < P) ? pd[i] : nd[i];
    float z[32];
    const float4* ha = (const float4*)(hp + (size_t)a * 32);
    const float4* hb = (const float4*)(hp + (size_t)b * 32);
    #pragma unroll
    for (int q = 0; q < 8; q++) {
        float4 x = ha[q], y = hb[q];
        z[q * 4 + 0] = x.x * y.x; z[q * 4 + 1] = x.y * y.y;
        z[q * 4 + 2] = x.z * y.z; z[q * 4 + 3] = x.w * y.w;
    }
    float z1[32];
    #pragma unroll
    for (int j = 0; j < 32; j++) {
        float s = b1[j];
        #pragma unroll
        for (int k = 0; k < 32; k++) s += z[k] * w1[k * 32 + j];
        z1[j] = fmaxf(s, 0.f);
    }
    #pragma unroll
    for (int j = 0; j < 32; j++) {
        float s = b2[j];
        #pragma unroll
        for (int k = 0; k < 32; k++) s += z1[k] * w2[k * 32 + j];
        z[j] = fmaxf(s, 0.f);
    }
    float s3 = bq3[0];
    #pragma unroll
    for (int j = 0; j < 32; j++) s3 += z[j] * w3[j];
    out[gid] = s3;
}

// ---------------- launch ----------------
extern "C" void kernel_launch(void* const* d_in, const int* in_sizes, int n_in,
                              void* d_out, int out_size, void* d_ws, size_t ws_size,
                              hipStream_t stream) {
    const float* x   = (const float*)d_in[0];
    const int* src   = (const int*)d_in[1];
    const int* dst   = (const int*)d_in[2];
    const int* psrc  = (const int*)d_in[3];
    const int* pdst  = (const int*)d_in[4];
    const int* nsrc  = (const int*)d_in[5];
    const int* ndst  = (const int*)d_in[6];
    const float* W[3]  = { (const float*)d_in[7],  (const float*)d_in[11], (const float*)d_in[15] };
    const float* al[3] = { (const float*)d_in[8],  (const float*)d_in[12], (const float*)d_in[16] };
    const float* ar[3] = { (const float*)d_in[9],  (const float*)d_in[13], (const float*)d_in[17] };
    const float* bb[3] = { (const float*)d_in[10], (const float*)d_in[14], (const float*)d_in[18] };
    const float* Wp  = (const float*)d_in[19];
    const float* bp  = (const float*)d_in[20];
    const float* Wq1 = (const float*)d_in[21];
    const float* bq1 = (const float*)d_in[22];
    const float* Wq2 = (const float*)d_in[23];
    const float* bq2 = (const float*)d_in[24];
    const float* Wq3 = (const float*)d_in[25];
    const float* bq3 = (const float*)d_in[26];
    float* out = (float*)d_out;

    const int N = in_sizes[0] / 128;
    const int E = in_sizes[1];
    const int P = in_sizes[3];

    size_t off = 0;
    auto alloc = [&](size_t bytes) {
        void* p = (char*)d_ws + off;
        off += (bytes + 255) & ~(size_t)255;
        return p;
    };
    float* bufF  = (float*)alloc((size_t)N * 128 * 4);
    float* bufH  = (float*)alloc((size_t)N * 128 * 4);
    float* elA   = (float*)alloc((size_t)N * 4 * 4);
    float* erA   = (float*)alloc((size_t)N * 4 * 4);
    float* hp    = (float*)alloc((size_t)N * 32 * 4);
    int* rowptr  = (int*)alloc((size_t)(N + 1) * 4);
    int* cursor  = (int*)alloc((size_t)(N + 1) * 4);
    int* csrc    = (int*)alloc((size_t)E * 4);
    int* deg     = (int*)alloc((size_t)N * 4);
    int* bsum    = (int*)alloc(1024 * 4);
    unsigned short* Bp = (unsigned short*)alloc(3 * 32768 * 2);
    (void)ws_size;

    const int NB_E4 = (E / 4 + 255) / 256;
    const int NB_N = (N + 255) / 256;

    hipMemsetAsync(deg, 0, (size_t)N * 4, stream);

    hist_k<<<NB_E4, 256, 0, stream>>>(dst, deg, E);
    scan1_k<<<NB_N, 256, 0, stream>>>(deg, rowptr, bsum, N);
    scan2_k<<<1, 512, 0, stream>>>(bsum, NB_N);
    scan3_k<<<NB_N, 256, 0, stream>>>(rowptr, cursor, bsum, N);
    fill_k<<<NB_E4, 256, 0, stream>>>(src, dst, cursor, csrc, E);
    wconv3_k<<<192, 256, 0, stream>>>(W[0], W[1], W[2], Bp);

    const int GEMM_B = (N + 127) / 128;
    const float* hin = x;
    for (int l = 0; l < 3; l++) {
        gemm_mfma_k<<<GEMM_B, 512, 0, stream>>>(hin, Bp + (size_t)l * 32768, al[l], ar[l], bufF, elA, erA, N);
        aggregate_k<<<(N + 3) / 4, 256, 0, stream>>>(bufF, elA, erA, rowptr, csrc, bb[l], bufH, N);
        hin = bufH;
    }
    proj_k<<<(N + 31) / 32, 256, 0, stream>>>(bufH, Wp, bp, hp, N);
    predictor_k<<<(2 * P + 255) / 256, 256, 0, stream>>>(hp, psrc, pdst, nsrc, ndst,
                                                         Wq1, bq1, Wq2, bq2, Wq3, bq3, out, P);
}